// Round 1
// baseline (397.190 us; speedup 1.0000x reference)
//
#include <hip/hip_runtime.h>

// Problem constants (fixed by setup_inputs): B=16, D=16, H=288, W=512, L=17
#define BB  16
#define DD  16
#define NN  (288*512)        // 147456 pixels per image
#define LL  17
#define QPI (NN/4)           // 36864 quad-pixels per image
#define GPB 48               // blocks per image
#define TPB 256

// ws layout (floats):
//   acc  [B][17][17]  (d<16: channel sums, d==16: count)   = 16*289
//   means[B][17][16]                                        = 16*272
//   wvec [B][17]                                            = 16*17

__global__ __launch_bounds__(TPB) void k_accum(const float* __restrict__ emb,
                                               const int* __restrict__ seg,
                                               float* __restrict__ acc) {
    // 8 LDS replicas of the padded [17][17] table: pad=17 makes bank =
    // (17*s+d)%32 injective in s (gcd(17,32)=1) -> no cross-address conflicts;
    // replicas (8 lanes each) cut same-address ds_add serialization.
    __shared__ float ls[8 * 289];
    const int tid = threadIdx.x;
    const int b = blockIdx.y;
    for (int i = tid; i < 8 * 289; i += TPB) ls[i] = 0.f;
    __syncthreads();

    float* base = ls + ((tid >> 3) & 7) * 289;
    const float* embb = emb + (size_t)b * DD * NN;
    const int*   segb = seg + (size_t)b * NN;

    for (int q = blockIdx.x * TPB + tid; q < QPI; q += GPB * TPB) {
        const int n = q * 4;
        int4 s4 = *(const int4*)(segb + n);
        const int o0 = s4.x * 17, o1 = s4.y * 17, o2 = s4.z * 17, o3 = s4.w * 17;
#pragma unroll
        for (int d = 0; d < DD; ++d) {
            float4 e = *(const float4*)(embb + (size_t)d * NN + n);
            atomicAdd(base + o0 + d, e.x);
            atomicAdd(base + o1 + d, e.y);
            atomicAdd(base + o2 + d, e.z);
            atomicAdd(base + o3 + d, e.w);
        }
        atomicAdd(base + o0 + 16, 1.f);
        atomicAdd(base + o1 + 16, 1.f);
        atomicAdd(base + o2 + 16, 1.f);
        atomicAdd(base + o3 + 16, 1.f);
    }
    __syncthreads();
    for (int i = tid; i < 289; i += TPB) {
        float v = 0.f;
#pragma unroll
        for (int r = 0; r < 8; ++r) v += ls[r * 289 + i];
        atomicAdd(acc + b * 289 + i, v);
    }
}

__global__ __launch_bounds__(64) void k_stats(const float* __restrict__ acc,
                                              float* __restrict__ means,
                                              float* __restrict__ wvec,
                                              float* __restrict__ out) {
    __shared__ float m[289];   // [l*17+d]: d<16 sums->means, d==16 count
    const int tid = threadIdx.x;
    const int b = blockIdx.x;
    for (int i = tid; i < 289; i += 64) m[i] = acc[b * 289 + i];
    __syncthreads();

    // means (each entry touched by exactly one thread; cnt slot untouched)
    for (int i = tid; i < 272; i += 64) {
        const int l = i >> 4, d = i & 15;
        const float c = m[l * 17 + 16];
        const float mv = m[l * 17 + d] / fmaxf(c, 1.f);
        m[l * 17 + d] = mv;
        means[b * 272 + i] = mv;
    }
    __syncthreads();

    int nl = 0;
#pragma unroll
    for (int l = 1; l < LL; ++l) nl += (m[l * 17 + 16] > 0.f) ? 1 : 0;
    const float nlf = (float)nl;

    if (tid < LL) {
        const int l = tid;
        const bool pres = (l != 0) && (m[l * 17 + 16] > 0.f);
        // folds: /cnt (per-label mean), /max(nl,1) (lane mean), /B (batch mean)
        const float w = pres ? 1.f / (fmaxf(m[l * 17 + 16], 1.f) * fmaxf(nlf, 1.f) * (float)BB)
                             : 0.f;
        wvec[b * 17 + l] = w;
    }

    // push (distance) term: 17x17 pairs
    float push = 0.f;
    for (int p = tid; p < 289; p += 64) {
        const int i = p / 17, j = p % 17;
        if (i != j && i > 0 && j > 0 && m[i * 17 + 16] > 0.f && m[j * 17 + 16] > 0.f) {
            float ss = 0.f;
#pragma unroll
            for (int d = 0; d < DD; ++d) {
                const float df = m[i * 17 + d] - m[j * 17 + d];
                ss += df * df;
            }
            const float t = fmaxf(1.5f - sqrtf(ss), 0.f);
            push += t * t;
        }
    }
#pragma unroll
    for (int off = 32; off > 0; off >>= 1) push += __shfl_down(push, off, 64);
    if (tid == 0 && nl > 1) {
        const float dist_l = push / (fmaxf(nlf * (nlf - 1.f), 1.f) * 2.f);
        atomicAdd(out, dist_l * (1.f / (float)BB));
    }
}

__global__ __launch_bounds__(TPB) void k_var(const float* __restrict__ emb,
                                             const int* __restrict__ seg,
                                             const float* __restrict__ means,
                                             const float* __restrict__ wvec,
                                             float* __restrict__ out) {
    __shared__ float m[289];   // padded [17][17] -> conflict-free random lookups
    __shared__ float wl[17];
    __shared__ float wsum[TPB / 64];
    const int tid = threadIdx.x;
    const int b = blockIdx.y;
    for (int i = tid; i < 272; i += TPB)
        m[(i >> 4) * 17 + (i & 15)] = means[b * 272 + i];
    if (tid < LL) wl[tid] = wvec[b * 17 + tid];
    __syncthreads();

    const float* embb = emb + (size_t)b * DD * NN;
    const int*   segb = seg + (size_t)b * NN;
    float accl = 0.f;

    for (int q = blockIdx.x * TPB + tid; q < QPI; q += GPB * TPB) {
        const int n = q * 4;
        int4 s4 = *(const int4*)(segb + n);
        const int o0 = s4.x * 17, o1 = s4.y * 17, o2 = s4.z * 17, o3 = s4.w * 17;
        float ss0 = 0.f, ss1 = 0.f, ss2 = 0.f, ss3 = 0.f;
#pragma unroll
        for (int d = 0; d < DD; ++d) {
            float4 e = *(const float4*)(embb + (size_t)d * NN + n);
            const float d0 = e.x - m[o0 + d]; ss0 += d0 * d0;
            const float d1 = e.y - m[o1 + d]; ss1 += d1 * d1;
            const float d2 = e.z - m[o2 + d]; ss2 += d2 * d2;
            const float d3 = e.w - m[o3 + d]; ss3 += d3 * d3;
        }
        float t;
        t = fmaxf(sqrtf(fmaxf(ss0, 1e-12f)) - 0.5f, 0.f); accl += t * t * wl[s4.x];
        t = fmaxf(sqrtf(fmaxf(ss1, 1e-12f)) - 0.5f, 0.f); accl += t * t * wl[s4.y];
        t = fmaxf(sqrtf(fmaxf(ss2, 1e-12f)) - 0.5f, 0.f); accl += t * t * wl[s4.z];
        t = fmaxf(sqrtf(fmaxf(ss3, 1e-12f)) - 0.5f, 0.f); accl += t * t * wl[s4.w];
    }
#pragma unroll
    for (int off = 32; off > 0; off >>= 1) accl += __shfl_down(accl, off, 64);
    if ((tid & 63) == 0) wsum[tid >> 6] = accl;
    __syncthreads();
    if (tid == 0) atomicAdd(out, wsum[0] + wsum[1] + wsum[2] + wsum[3]);
}

extern "C" void kernel_launch(void* const* d_in, const int* in_sizes, int n_in,
                              void* d_out, int out_size, void* d_ws, size_t ws_size,
                              hipStream_t stream) {
    const float* emb = (const float*)d_in[0];
    const int*   seg = (const int*)d_in[1];
    float* out = (float*)d_out;

    float* acc   = (float*)d_ws;           // 16*289
    float* means = acc + BB * 289;         // 16*272
    float* wvec  = means + BB * 272;       // 16*17

    hipMemsetAsync(acc, 0, (size_t)BB * 289 * sizeof(float), stream);
    hipMemsetAsync(out, 0, sizeof(float), stream);

    k_accum<<<dim3(GPB, BB), TPB, 0, stream>>>(emb, seg, acc);
    k_stats<<<BB, 64, 0, stream>>>(acc, means, wvec, out);
    k_var  <<<dim3(GPB, BB), TPB, 0, stream>>>(emb, seg, means, wvec, out);
}

// Round 2
// 282.197 us; speedup vs baseline: 1.4075x; 1.4075x over previous
//
#include <hip/hip_runtime.h>

// B=16, D=16, H=288, W=512, L=17 (fixed by setup_inputs)
#define BB  16
#define DD  16
#define NN  (288*512)      // 147456 pixels/image
#define LL  17
#define QPI (NN/4)         // 36864 quads/image
#define PB  48             // blocks per image (accum & var) -> 768 blocks = 3/CU
#define PXB (NN/PB)        // 3072 pixels per accum block
#define TILE 1024          // staged seg tile (ints)
#define TPB 256

// ws float layout:
//   part  [B][PB][289]  (i = l*16+d for sums, 272+l for counts)
//   gmean [B][272]      (l*16+d)
//   gw    [B][17]
//   dvec  [B]
//   vpart [B*PB]

__global__ __launch_bounds__(TPB) void k_accum(const float* __restrict__ emb,
                                               const int* __restrict__ seg,
                                               float* __restrict__ part) {
    __shared__ int slab[TILE];
    const int tid  = threadIdx.x;
    const int b    = blockIdx.y;
    const int blk  = blockIdx.x;
    const int dgrp = tid >> 6;   // wave id: owns channels 4*dgrp .. 4*dgrp+3
    const int j    = tid & 63;
    const float* embb = emb + (size_t)b * DD * NN;
    const int*   segb = seg + (size_t)b * NN;
    const int base0 = blk * PXB;

    // register accumulators: 17 labels x 4 channels (+ counts on wave 0)
    float a0[LL], a1[LL], a2[LL], a3[LL], cf[LL];
#pragma unroll
    for (int l = 0; l < LL; ++l) { a0[l]=0.f; a1[l]=0.f; a2[l]=0.f; a3[l]=0.f; cf[l]=0.f; }

    const float* r0 = embb + (size_t)(dgrp*4+0) * NN;
    const float* r1 = embb + (size_t)(dgrp*4+1) * NN;
    const float* r2 = embb + (size_t)(dgrp*4+2) * NN;
    const float* r3 = embb + (size_t)(dgrp*4+3) * NN;

    for (int t = 0; t < PXB / TILE; ++t) {
        const int tb = base0 + t * TILE;
        *(int4*)(slab + tid * 4) = *(const int4*)(segb + tb + tid * 4);
        __syncthreads();
#pragma unroll
        for (int s = 0; s < TILE / 256; ++s) {
            const int p = s * 256 + j * 4;
            const int4   s4 = *(const int4*)(slab + p);
            const float4 e0 = *(const float4*)(r0 + tb + p);
            const float4 e1 = *(const float4*)(r1 + tb + p);
            const float4 e2 = *(const float4*)(r2 + tb + p);
            const float4 e3 = *(const float4*)(r3 + tb + p);
#pragma unroll
            for (int l = 0; l < LL; ++l) {
                const float mx = (s4.x == l) ? 1.f : 0.f;
                const float my = (s4.y == l) ? 1.f : 0.f;
                const float mz = (s4.z == l) ? 1.f : 0.f;
                const float mw = (s4.w == l) ? 1.f : 0.f;
                a0[l] = fmaf(mx, e0.x, fmaf(my, e0.y, fmaf(mz, e0.z, fmaf(mw, e0.w, a0[l]))));
                a1[l] = fmaf(mx, e1.x, fmaf(my, e1.y, fmaf(mz, e1.z, fmaf(mw, e1.w, a1[l]))));
                a2[l] = fmaf(mx, e2.x, fmaf(my, e2.y, fmaf(mz, e2.z, fmaf(mw, e2.w, a2[l]))));
                a3[l] = fmaf(mx, e3.x, fmaf(my, e3.y, fmaf(mz, e3.z, fmaf(mw, e3.w, a3[l]))));
            }
            if (dgrp == 0) {   // wave-uniform branch: counts on wave 0 only
#pragma unroll
                for (int l = 0; l < LL; ++l)
                    cf[l] += ((s4.x==l)?1.f:0.f) + ((s4.y==l)?1.f:0.f)
                           + ((s4.z==l)?1.f:0.f) + ((s4.w==l)?1.f:0.f);
            }
        }
        __syncthreads();
    }

    // wave-level reduce (64 lanes of a wave all own the same 4 channels)
    float* pp = part + ((size_t)b * PB + blk) * 289;
#pragma unroll
    for (int l = 0; l < LL; ++l) {
        float v0 = a0[l], v1 = a1[l], v2 = a2[l], v3 = a3[l];
#pragma unroll
        for (int off = 32; off; off >>= 1) {
            v0 += __shfl_down(v0, off, 64);
            v1 += __shfl_down(v1, off, 64);
            v2 += __shfl_down(v2, off, 64);
            v3 += __shfl_down(v3, off, 64);
        }
        if (j == 0) {
            pp[l*16 + dgrp*4 + 0] = v0;
            pp[l*16 + dgrp*4 + 1] = v1;
            pp[l*16 + dgrp*4 + 2] = v2;
            pp[l*16 + dgrp*4 + 3] = v3;
        }
        float c = cf[l];
#pragma unroll
        for (int off = 32; off; off >>= 1) c += __shfl_down(c, off, 64);
        if (tid == 0) pp[272 + l] = c;
    }
}

__global__ __launch_bounds__(64) void k_stats(const float* __restrict__ part,
                                              float* __restrict__ gmean,
                                              float* __restrict__ gw,
                                              float* __restrict__ dvec) {
    __shared__ float mm[289];   // [l*17+d], d==16 -> count
    const int tid = threadIdx.x;
    const int b = blockIdx.x;
    for (int i = tid; i < 289; i += 64) {
        const int l = i / 17, d = i % 17;
        const int isrc = (d < 16) ? (l * 16 + d) : (272 + l);
        float v = 0.f;
        for (int p = 0; p < PB; ++p) v += part[((size_t)b * PB + p) * 289 + isrc];
        mm[i] = v;
    }
    __syncthreads();
    for (int i = tid; i < 272; i += 64) {
        const int l = i >> 4, d = i & 15;
        const float c = mm[l * 17 + 16];
        const float mv = mm[l * 17 + d] / fmaxf(c, 1.f);
        mm[l * 17 + d] = mv;
        gmean[(size_t)b * 272 + i] = mv;
    }
    __syncthreads();

    int nl = 0;
#pragma unroll
    for (int l = 1; l < LL; ++l) nl += (mm[l * 17 + 16] > 0.f) ? 1 : 0;
    const float nlf = (float)nl;

    if (tid < LL) {
        const bool pres = (tid != 0) && (mm[tid * 17 + 16] > 0.f);
        gw[(size_t)b * 17 + tid] = pres
            ? 1.f / (fmaxf(mm[tid * 17 + 16], 1.f) * fmaxf(nlf, 1.f) * (float)BB) : 0.f;
    }

    float push = 0.f;
    for (int p = tid; p < 289; p += 64) {
        const int i = p / 17, jj = p % 17;
        if (i != jj && i > 0 && jj > 0 && mm[i*17+16] > 0.f && mm[jj*17+16] > 0.f) {
            float ss = 0.f;
#pragma unroll
            for (int d = 0; d < DD; ++d) {
                const float df = mm[i*17+d] - mm[jj*17+d];
                ss += df * df;
            }
            const float t = fmaxf(1.5f - sqrtf(ss), 0.f);
            push += t * t;
        }
    }
#pragma unroll
    for (int off = 32; off; off >>= 1) push += __shfl_down(push, off, 64);
    if (tid == 0)
        dvec[b] = (nl > 1) ? push / (fmaxf(nlf * (nlf - 1.f), 1.f) * 2.f * (float)BB) : 0.f;
}

__global__ __launch_bounds__(TPB) void k_var(const float* __restrict__ emb,
                                             const int* __restrict__ seg,
                                             const float* __restrict__ gmean,
                                             const float* __restrict__ gw,
                                             float* __restrict__ vpart) {
    __shared__ float m[289];     // padded [17][17]: conflict-free random lookups
    __shared__ float wl[17];
    __shared__ float wsum[TPB / 64];
    const int tid = threadIdx.x;
    const int b = blockIdx.y;
    for (int i = tid; i < 272; i += TPB)
        m[(i >> 4) * 17 + (i & 15)] = gmean[(size_t)b * 272 + i];
    if (tid < LL) wl[tid] = gw[(size_t)b * 17 + tid];
    __syncthreads();

    const float* embb = emb + (size_t)b * DD * NN;
    const int*   segb = seg + (size_t)b * NN;
    float accl = 0.f;

    for (int q = blockIdx.x * TPB + tid; q < QPI; q += PB * TPB) {
        const int n = q * 4;
        const int4 s4 = *(const int4*)(segb + n);
        const int o0 = s4.x * 17, o1 = s4.y * 17, o2 = s4.z * 17, o3 = s4.w * 17;
        float ss0 = 0.f, ss1 = 0.f, ss2 = 0.f, ss3 = 0.f;
#pragma unroll
        for (int d = 0; d < DD; ++d) {
            const float4 e = *(const float4*)(embb + (size_t)d * NN + n);
            const float d0 = e.x - m[o0 + d]; ss0 += d0 * d0;
            const float d1 = e.y - m[o1 + d]; ss1 += d1 * d1;
            const float d2 = e.z - m[o2 + d]; ss2 += d2 * d2;
            const float d3 = e.w - m[o3 + d]; ss3 += d3 * d3;
        }
        float t;
        t = fmaxf(sqrtf(fmaxf(ss0, 1e-12f)) - 0.5f, 0.f); accl += t * t * wl[s4.x];
        t = fmaxf(sqrtf(fmaxf(ss1, 1e-12f)) - 0.5f, 0.f); accl += t * t * wl[s4.y];
        t = fmaxf(sqrtf(fmaxf(ss2, 1e-12f)) - 0.5f, 0.f); accl += t * t * wl[s4.z];
        t = fmaxf(sqrtf(fmaxf(ss3, 1e-12f)) - 0.5f, 0.f); accl += t * t * wl[s4.w];
    }
#pragma unroll
    for (int off = 32; off; off >>= 1) accl += __shfl_down(accl, off, 64);
    if ((tid & 63) == 0) wsum[tid >> 6] = accl;
    __syncthreads();
    if (tid == 0)
        vpart[(size_t)b * PB + blockIdx.x] = wsum[0] + wsum[1] + wsum[2] + wsum[3];
}

__global__ __launch_bounds__(TPB) void k_final(const float* __restrict__ vpart,
                                               const float* __restrict__ dvec,
                                               float* __restrict__ out) {
    __shared__ float ws4[TPB / 64];
    float v = 0.f;
    for (int i = threadIdx.x; i < BB * PB; i += TPB) v += vpart[i];
    if (threadIdx.x < BB) v += dvec[threadIdx.x];
#pragma unroll
    for (int off = 32; off; off >>= 1) v += __shfl_down(v, off, 64);
    if ((threadIdx.x & 63) == 0) ws4[threadIdx.x >> 6] = v;
    __syncthreads();
    if (threadIdx.x == 0) out[0] = ws4[0] + ws4[1] + ws4[2] + ws4[3];
}

extern "C" void kernel_launch(void* const* d_in, const int* in_sizes, int n_in,
                              void* d_out, int out_size, void* d_ws, size_t ws_size,
                              hipStream_t stream) {
    const float* emb = (const float*)d_in[0];
    const int*   seg = (const int*)d_in[1];
    float* out = (float*)d_out;

    float* part  = (float*)d_ws;              // 16*48*289
    float* gmean = part + BB * PB * 289;      // 16*272
    float* gw    = gmean + BB * 272;          // 16*17
    float* dvec  = gw + BB * 17;              // 16
    float* vpart = dvec + BB;                 // 16*48

    k_accum<<<dim3(PB, BB), TPB, 0, stream>>>(emb, seg, part);
    k_stats<<<BB, 64, 0, stream>>>(part, gmean, gw, dvec);
    k_var  <<<dim3(PB, BB), TPB, 0, stream>>>(emb, seg, gmean, gw, vpart);
    k_final<<<1, TPB, 0, stream>>>(vpart, dvec, out);
}

// Round 3
// 252.389 us; speedup vs baseline: 1.5737x; 1.1181x over previous
//
#include <hip/hip_runtime.h>

// B=16, D=16, H=288, W=512, L=17 (fixed by setup_inputs)
#define BB   16
#define DD   16
#define NN   (288*512)     // 147456 pixels/image
#define LL   17
#define TPB  256
// k_accum partitioning
#define PB   96            // blocks/image -> 1536 blocks = 6/CU
#define PXB  (NN/PB)       // 1536 pixels/block
#define TILE 512           // staged seg tile
// k_var partitioning
#define PBV  144           // blocks/image; 1024 px/block = exactly one sweep of 256 thr x 4 px
#define NREP 16            // LDS replicas in k_accum

#define FSCALE 32768.0f
#define INV_FSCALE (1.0f/32768.0f)

// ws layout:
//   acc   int  [B][289]   (l*17+d sums for d<16, count at l*17+16)
//   gmean float[B][272]   (l*16+d)
//   gw    float[B][17]
//   dvec  float[B]
//   vpart float[B][PBV]

__global__ __launch_bounds__(TPB) void k_accum(const float* __restrict__ emb,
                                               const int* __restrict__ seg,
                                               int* __restrict__ acc) {
    __shared__ int slab[TILE];
    __shared__ int tab[NREP * 289];   // pad-17 rows: bank=(rep+17s+c)%32, light conflicts
    const int tid  = threadIdx.x;
    const int b    = blockIdx.y;
    const int blk  = blockIdx.x;
    const int dgrp = tid >> 6;        // wave owns channels 4*dgrp..+3
    const int j    = tid & 63;
    int* trep = tab + (j & (NREP - 1)) * 289;

    for (int i = tid; i < NREP * 289; i += TPB) tab[i] = 0;

    const float* embb = emb + (size_t)b * DD * NN;
    const int*   segb = seg + (size_t)b * NN;
    const int base0 = blk * PXB;
    const float* r0 = embb + (size_t)(dgrp * 4 + 0) * NN;
    const float* r1 = embb + (size_t)(dgrp * 4 + 1) * NN;
    const float* r2 = embb + (size_t)(dgrp * 4 + 2) * NN;
    const float* r3 = embb + (size_t)(dgrp * 4 + 3) * NN;
    __syncthreads();

    for (int t = 0; t < PXB / TILE; ++t) {
        const int tb = base0 + t * TILE;
        if (tid < TILE / 4)
            *(int4*)(slab + tid * 4) = *(const int4*)(segb + tb + tid * 4);
        __syncthreads();
#pragma unroll
        for (int s = 0; s < TILE / 256; ++s) {
            const int p = s * 256 + j * 4;
            const int4   s4 = *(const int4*)(slab + p);
            const float4 e0 = *(const float4*)(r0 + tb + p);
            const float4 e1 = *(const float4*)(r1 + tb + p);
            const float4 e2 = *(const float4*)(r2 + tb + p);
            const float4 e3 = *(const float4*)(r3 + tb + p);
            const int o0 = s4.x * 17 + dgrp * 4;
            const int o1 = s4.y * 17 + dgrp * 4;
            const int o2 = s4.z * 17 + dgrp * 4;
            const int o3 = s4.w * 17 + dgrp * 4;
            // native ds_add_u32 (int atomics never CAS-loop), fixed-point 2^15
            atomicAdd(trep + o0 + 0, __float2int_rn(e0.x * FSCALE));
            atomicAdd(trep + o0 + 1, __float2int_rn(e1.x * FSCALE));
            atomicAdd(trep + o0 + 2, __float2int_rn(e2.x * FSCALE));
            atomicAdd(trep + o0 + 3, __float2int_rn(e3.x * FSCALE));
            atomicAdd(trep + o1 + 0, __float2int_rn(e0.y * FSCALE));
            atomicAdd(trep + o1 + 1, __float2int_rn(e1.y * FSCALE));
            atomicAdd(trep + o1 + 2, __float2int_rn(e2.y * FSCALE));
            atomicAdd(trep + o1 + 3, __float2int_rn(e3.y * FSCALE));
            atomicAdd(trep + o2 + 0, __float2int_rn(e0.z * FSCALE));
            atomicAdd(trep + o2 + 1, __float2int_rn(e1.z * FSCALE));
            atomicAdd(trep + o2 + 2, __float2int_rn(e2.z * FSCALE));
            atomicAdd(trep + o2 + 3, __float2int_rn(e3.z * FSCALE));
            atomicAdd(trep + o3 + 0, __float2int_rn(e0.w * FSCALE));
            atomicAdd(trep + o3 + 1, __float2int_rn(e1.w * FSCALE));
            atomicAdd(trep + o3 + 2, __float2int_rn(e2.w * FSCALE));
            atomicAdd(trep + o3 + 3, __float2int_rn(e3.w * FSCALE));
            if (dgrp == 0) {   // wave-uniform: counts once per pixel
                atomicAdd(trep + s4.x * 17 + 16, 1);
                atomicAdd(trep + s4.y * 17 + 16, 1);
                atomicAdd(trep + s4.z * 17 + 16, 1);
                atomicAdd(trep + s4.w * 17 + 16, 1);
            }
        }
        __syncthreads();
    }

    for (int i = tid; i < 289; i += TPB) {
        int v = 0;
#pragma unroll
        for (int r = 0; r < NREP; ++r) v += tab[r * 289 + i];
        atomicAdd(acc + b * 289 + i, v);   // native global int atomic
    }
}

__global__ __launch_bounds__(64) void k_stats(const int* __restrict__ acc,
                                              float* __restrict__ gmean,
                                              float* __restrict__ gw,
                                              float* __restrict__ dvec) {
    __shared__ float mm[289];   // [l*17+d], d==16 -> count
    const int tid = threadIdx.x;
    const int b = blockIdx.x;
    for (int i = tid; i < 289; i += 64) {
        const int raw = acc[b * 289 + i];
        mm[i] = (i % 17 == 16) ? (float)raw : (float)raw * INV_FSCALE;
    }
    __syncthreads();
    for (int i = tid; i < 272; i += 64) {
        const int l = i >> 4, d = i & 15;
        const float c = mm[l * 17 + 16];
        const float mv = mm[l * 17 + d] / fmaxf(c, 1.f);
        mm[l * 17 + d] = mv;
        gmean[(size_t)b * 272 + i] = mv;
    }
    __syncthreads();

    int nl = 0;
#pragma unroll
    for (int l = 1; l < LL; ++l) nl += (mm[l * 17 + 16] > 0.f) ? 1 : 0;
    const float nlf = (float)nl;

    if (tid < LL) {
        const bool pres = (tid != 0) && (mm[tid * 17 + 16] > 0.f);
        gw[(size_t)b * 17 + tid] = pres
            ? 1.f / (fmaxf(mm[tid * 17 + 16], 1.f) * fmaxf(nlf, 1.f) * (float)BB) : 0.f;
    }

    float push = 0.f;
    for (int p = tid; p < 289; p += 64) {
        const int i = p / 17, jj = p % 17;
        if (i != jj && i > 0 && jj > 0 && mm[i*17+16] > 0.f && mm[jj*17+16] > 0.f) {
            float ss = 0.f;
#pragma unroll
            for (int d = 0; d < DD; ++d) {
                const float df = mm[i*17+d] - mm[jj*17+d];
                ss += df * df;
            }
            const float t = fmaxf(1.5f - sqrtf(ss), 0.f);
            push += t * t;
        }
    }
#pragma unroll
    for (int off = 32; off; off >>= 1) push += __shfl_down(push, off, 64);
    if (tid == 0)
        dvec[b] = (nl > 1) ? push / (fmaxf(nlf * (nlf - 1.f), 1.f) * 2.f * (float)BB) : 0.f;
}

__global__ __launch_bounds__(TPB) void k_var(const float* __restrict__ emb,
                                             const int* __restrict__ seg,
                                             const float* __restrict__ gmean,
                                             const float* __restrict__ gw,
                                             float* __restrict__ vpart) {
    __shared__ float m[289];     // padded [17][17]: conflict-free random lookups
    __shared__ float wl[17];
    __shared__ float wsum[TPB / 64];
    const int tid = threadIdx.x;
    const int b = blockIdx.y;
    for (int i = tid; i < 272; i += TPB)
        m[(i >> 4) * 17 + (i & 15)] = gmean[(size_t)b * 272 + i];
    if (tid < LL) wl[tid] = gw[(size_t)b * 17 + tid];
    __syncthreads();

    const float* embb = emb + (size_t)b * DD * NN;
    const int*   segb = seg + (size_t)b * NN;

    const int n = blockIdx.x * (TPB * 4) + tid * 4;   // exactly one sweep: 144*1024 = NN
    const int4 s4 = *(const int4*)(segb + n);
    const int o0 = s4.x * 17, o1 = s4.y * 17, o2 = s4.z * 17, o3 = s4.w * 17;
    float ss0 = 0.f, ss1 = 0.f, ss2 = 0.f, ss3 = 0.f;
#pragma unroll
    for (int d = 0; d < DD; ++d) {
        const float4 e = *(const float4*)(embb + (size_t)d * NN + n);
        const float d0 = e.x - m[o0 + d]; ss0 += d0 * d0;
        const float d1 = e.y - m[o1 + d]; ss1 += d1 * d1;
        const float d2 = e.z - m[o2 + d]; ss2 += d2 * d2;
        const float d3 = e.w - m[o3 + d]; ss3 += d3 * d3;
    }
    float accl = 0.f, t;
    t = fmaxf(sqrtf(fmaxf(ss0, 1e-12f)) - 0.5f, 0.f); accl += t * t * wl[s4.x];
    t = fmaxf(sqrtf(fmaxf(ss1, 1e-12f)) - 0.5f, 0.f); accl += t * t * wl[s4.y];
    t = fmaxf(sqrtf(fmaxf(ss2, 1e-12f)) - 0.5f, 0.f); accl += t * t * wl[s4.z];
    t = fmaxf(sqrtf(fmaxf(ss3, 1e-12f)) - 0.5f, 0.f); accl += t * t * wl[s4.w];

#pragma unroll
    for (int off = 32; off; off >>= 1) accl += __shfl_down(accl, off, 64);
    if ((tid & 63) == 0) wsum[tid >> 6] = accl;
    __syncthreads();
    if (tid == 0)
        vpart[(size_t)b * PBV + blockIdx.x] = wsum[0] + wsum[1] + wsum[2] + wsum[3];
}

__global__ __launch_bounds__(TPB) void k_final(const float* __restrict__ vpart,
                                               const float* __restrict__ dvec,
                                               float* __restrict__ out) {
    __shared__ float ws4[TPB / 64];
    float v = 0.f;
    for (int i = threadIdx.x; i < BB * PBV; i += TPB) v += vpart[i];
    if (threadIdx.x < BB) v += dvec[threadIdx.x];
#pragma unroll
    for (int off = 32; off; off >>= 1) v += __shfl_down(v, off, 64);
    if ((threadIdx.x & 63) == 0) ws4[threadIdx.x >> 6] = v;
    __syncthreads();
    if (threadIdx.x == 0) out[0] = ws4[0] + ws4[1] + ws4[2] + ws4[3];
}

extern "C" void kernel_launch(void* const* d_in, const int* in_sizes, int n_in,
                              void* d_out, int out_size, void* d_ws, size_t ws_size,
                              hipStream_t stream) {
    const float* emb = (const float*)d_in[0];
    const int*   seg = (const int*)d_in[1];
    float* out = (float*)d_out;

    int*   acc   = (int*)d_ws;                        // 16*289 ints
    float* gmean = (float*)(acc + BB * 289);          // 16*272
    float* gw    = gmean + BB * 272;                  // 16*17
    float* dvec  = gw + BB * 17;                      // 16
    float* vpart = dvec + BB;                         // 16*144

    hipMemsetAsync(acc, 0, (size_t)BB * 289 * sizeof(int), stream);

    k_accum<<<dim3(PB, BB), TPB, 0, stream>>>(emb, seg, acc);
    k_stats<<<BB, 64, 0, stream>>>(acc, gmean, gw, dvec);
    k_var  <<<dim3(PBV, BB), TPB, 0, stream>>>(emb, seg, gmean, gw, vpart);
    k_final<<<1, TPB, 0, stream>>>(vpart, dvec, out);
}

// Round 4
// 246.169 us; speedup vs baseline: 1.6135x; 1.0253x over previous
//
#include <hip/hip_runtime.h>

// B=16, D=16, H=288, W=512, L=17 (fixed by setup_inputs)
#define BB   16
#define DD   16
#define NN   (288*512)     // 147456 pixels/image
#define LL   17
#define TPB  256
#define PB   96            // accum blocks/image: 1536 blocks = 6/CU
#define QB   (NN/4/PB)     // 384 quads/block -> 6 iters/wave of 64 lanes
#define PBV  144           // var blocks/image: 1024 px/block, one-shot sweep
#define NREP 8             // LDS table replicas in k_accum

#define FSCALE 32768.0f
#define INV_FSCALE (1.0f/32768.0f)

// ws layout:
//   acc   int  [B][289]   (l*17+d sums for d<16, count at l*17+16)
//   vpart float[B][PBV]

__global__ __launch_bounds__(TPB) void k_accum(const float* __restrict__ emb,
                                               const int* __restrict__ seg,
                                               int* __restrict__ acc) {
    __shared__ int tab[NREP * 289];   // pad-17 rows: injective label->bank (gcd(17,32)=1)
    const int tid  = threadIdx.x;
    const int b    = blockIdx.y;
    const int blk  = blockIdx.x;
    const int dgrp = tid >> 6;        // wave owns channels 4*dgrp..+3 (wave-uniform)
    const int j    = tid & 63;
    int* trep = tab + (j & (NREP - 1)) * 289;

    for (int i = tid; i < NREP * 289; i += TPB) tab[i] = 0;

    const float* embb = emb + (size_t)b * DD * NN;
    const int*   segb = seg + (size_t)b * NN;
    const float* r0 = embb + (size_t)(dgrp * 4 + 0) * NN;
    const float* r1 = embb + (size_t)(dgrp * 4 + 1) * NN;
    const float* r2 = embb + (size_t)(dgrp * 4 + 2) * NN;
    const float* r3 = embb + (size_t)(dgrp * 4 + 3) * NN;
    const int q0 = blk * QB;
    __syncthreads();

    // no barriers in the hot loop: independent iterations pipeline freely
#pragma unroll
    for (int it = 0; it < QB / 64; ++it) {
        const int n = (q0 + it * 64 + j) * 4;
        const int4   s4 = *(const int4*)(segb + n);   // L1-broadcast across waves
        const float4 e0 = *(const float4*)(r0 + n);
        const float4 e1 = *(const float4*)(r1 + n);
        const float4 e2 = *(const float4*)(r2 + n);
        const float4 e3 = *(const float4*)(r3 + n);
        const int ch = dgrp * 4;
        const int o0 = s4.x * 17 + ch;
        const int o1 = s4.y * 17 + ch;
        const int o2 = s4.z * 17 + ch;
        const int o3 = s4.w * 17 + ch;
        // native ds_add_u32 (int atomics never CAS-loop), fixed-point 2^15
        atomicAdd(trep + o0 + 0, __float2int_rn(e0.x * FSCALE));
        atomicAdd(trep + o0 + 1, __float2int_rn(e1.x * FSCALE));
        atomicAdd(trep + o0 + 2, __float2int_rn(e2.x * FSCALE));
        atomicAdd(trep + o0 + 3, __float2int_rn(e3.x * FSCALE));
        atomicAdd(trep + o1 + 0, __float2int_rn(e0.y * FSCALE));
        atomicAdd(trep + o1 + 1, __float2int_rn(e1.y * FSCALE));
        atomicAdd(trep + o1 + 2, __float2int_rn(e2.y * FSCALE));
        atomicAdd(trep + o1 + 3, __float2int_rn(e3.y * FSCALE));
        atomicAdd(trep + o2 + 0, __float2int_rn(e0.z * FSCALE));
        atomicAdd(trep + o2 + 1, __float2int_rn(e1.z * FSCALE));
        atomicAdd(trep + o2 + 2, __float2int_rn(e2.z * FSCALE));
        atomicAdd(trep + o2 + 3, __float2int_rn(e3.z * FSCALE));
        atomicAdd(trep + o3 + 0, __float2int_rn(e0.w * FSCALE));
        atomicAdd(trep + o3 + 1, __float2int_rn(e1.w * FSCALE));
        atomicAdd(trep + o3 + 2, __float2int_rn(e2.w * FSCALE));
        atomicAdd(trep + o3 + 3, __float2int_rn(e3.w * FSCALE));
        if (dgrp == 0) {   // wave-uniform: counts once per pixel
            atomicAdd(trep + s4.x * 17 + 16, 1);
            atomicAdd(trep + s4.y * 17 + 16, 1);
            atomicAdd(trep + s4.z * 17 + 16, 1);
            atomicAdd(trep + s4.w * 17 + 16, 1);
        }
    }
    __syncthreads();

    for (int i = tid; i < 289; i += TPB) {
        int v = 0;
#pragma unroll
        for (int r = 0; r < NREP; ++r) v += tab[r * 289 + i];
        atomicAdd(acc + b * 289 + i, v);   // native global int atomic, 16x289 addrs
    }
}

// k_var with fused stats prologue: every block derives means/weights from acc
// (289 ints, L2-hot); push term computed once per image by blockIdx.x==0.
__global__ __launch_bounds__(TPB) void k_var(const float* __restrict__ emb,
                                             const int* __restrict__ seg,
                                             const int* __restrict__ acc,
                                             float* __restrict__ vpart) {
    __shared__ float m[289];     // padded [17][17]: means, count at d==16
    __shared__ float wl[17];
    __shared__ float wsum[TPB / 64];
    const int tid = threadIdx.x;
    const int b = blockIdx.y;

    for (int i = tid; i < 289; i += TPB) {
        const int raw = acc[b * 289 + i];
        m[i] = (i % 17 == 16) ? (float)raw : (float)raw * INV_FSCALE;
    }
    __syncthreads();
    for (int i = tid; i < 272; i += TPB) {       // each i touched exactly once
        const int l = i >> 4, d = i & 15;
        m[l * 17 + d] /= fmaxf(m[l * 17 + 16], 1.f);
    }
    __syncthreads();

    int nl = 0;
#pragma unroll
    for (int l = 1; l < LL; ++l) nl += (m[l * 17 + 16] > 0.f) ? 1 : 0;
    const float nlf = (float)nl;
    if (tid < LL) {
        const bool pres = (tid != 0) && (m[tid * 17 + 16] > 0.f);
        wl[tid] = pres ? 1.f / (fmaxf(m[tid * 17 + 16], 1.f) * fmaxf(nlf, 1.f) * (float)BB)
                       : 0.f;
    }
    __syncthreads();

    const float* embb = emb + (size_t)b * DD * NN;
    const int*   segb = seg + (size_t)b * NN;

    const int n = blockIdx.x * (TPB * 4) + tid * 4;   // 144*1024 = NN exactly
    const int4 s4 = *(const int4*)(segb + n);
    const int o0 = s4.x * 17, o1 = s4.y * 17, o2 = s4.z * 17, o3 = s4.w * 17;
    float ss0 = 0.f, ss1 = 0.f, ss2 = 0.f, ss3 = 0.f;
#pragma unroll
    for (int d = 0; d < DD; ++d) {
        const float4 e = *(const float4*)(embb + (size_t)d * NN + n);
        const float d0 = e.x - m[o0 + d]; ss0 += d0 * d0;
        const float d1 = e.y - m[o1 + d]; ss1 += d1 * d1;
        const float d2 = e.z - m[o2 + d]; ss2 += d2 * d2;
        const float d3 = e.w - m[o3 + d]; ss3 += d3 * d3;
    }
    float accl = 0.f, t;
    t = fmaxf(sqrtf(fmaxf(ss0, 1e-12f)) - 0.5f, 0.f); accl += t * t * wl[s4.x];
    t = fmaxf(sqrtf(fmaxf(ss1, 1e-12f)) - 0.5f, 0.f); accl += t * t * wl[s4.y];
    t = fmaxf(sqrtf(fmaxf(ss2, 1e-12f)) - 0.5f, 0.f); accl += t * t * wl[s4.z];
    t = fmaxf(sqrtf(fmaxf(ss3, 1e-12f)) - 0.5f, 0.f); accl += t * t * wl[s4.w];

    // push (distance) term, once per image, folded into block-0's partial
    if (blockIdx.x == 0 && nl > 1) {
        float push = 0.f;
        for (int p = tid; p < 289; p += TPB) {
            const int i = p / 17, jj = p % 17;
            if (i != jj && i > 0 && jj > 0 && m[i*17+16] > 0.f && m[jj*17+16] > 0.f) {
                float ss = 0.f;
#pragma unroll
                for (int d = 0; d < DD; ++d) {
                    const float df = m[i*17+d] - m[jj*17+d];
                    ss += df * df;
                }
                const float u = fmaxf(1.5f - sqrtf(ss), 0.f);
                push += u * u;
            }
        }
        accl += push / (fmaxf(nlf * (nlf - 1.f), 1.f) * 2.f * (float)BB);
    }

#pragma unroll
    for (int off = 32; off; off >>= 1) accl += __shfl_down(accl, off, 64);
    if ((tid & 63) == 0) wsum[tid >> 6] = accl;
    __syncthreads();
    if (tid == 0)
        vpart[(size_t)b * PBV + blockIdx.x] = wsum[0] + wsum[1] + wsum[2] + wsum[3];
}

__global__ __launch_bounds__(TPB) void k_final(const float* __restrict__ vpart,
                                               float* __restrict__ out) {
    __shared__ float ws4[TPB / 64];
    float v = 0.f;
    for (int i = threadIdx.x; i < BB * PBV; i += TPB) v += vpart[i];
#pragma unroll
    for (int off = 32; off; off >>= 1) v += __shfl_down(v, off, 64);
    if ((threadIdx.x & 63) == 0) ws4[threadIdx.x >> 6] = v;
    __syncthreads();
    if (threadIdx.x == 0) out[0] = ws4[0] + ws4[1] + ws4[2] + ws4[3];
}

extern "C" void kernel_launch(void* const* d_in, const int* in_sizes, int n_in,
                              void* d_out, int out_size, void* d_ws, size_t ws_size,
                              hipStream_t stream) {
    const float* emb = (const float*)d_in[0];
    const int*   seg = (const int*)d_in[1];
    float* out = (float*)d_out;

    int*   acc   = (int*)d_ws;                 // 16*289 ints
    float* vpart = (float*)(acc + BB * 289);   // 16*144 floats

    hipMemsetAsync(acc, 0, (size_t)BB * 289 * sizeof(int), stream);

    k_accum<<<dim3(PB, BB), TPB, 0, stream>>>(emb, seg, acc);
    k_var  <<<dim3(PBV, BB), TPB, 0, stream>>>(emb, seg, acc, vpart);
    k_final<<<1, TPB, 0, stream>>>(vpart, out);
}